// Round 1
// baseline (655.595 us; speedup 1.0000x reference)
//
#include <hip/hip_runtime.h>
#include <math.h>

#define NA 16
#define NS 64
#define NB 100
#define NE 12
#define ML 20
#define DD 512
#define NC (NA*NE)   /* 192 */
#define NR (NA*NS)   /* 1024 */
#define EPSF 1e-5f
#define DELTA_F 0.2f

// ---------- helpers ----------
__device__ inline void wave_minmax64(float v, float& mn, float& mx){
  mn = v; mx = v;
  #pragma unroll
  for (int off = 32; off > 0; off >>= 1){
    mn = fminf(mn, __shfl_xor(mn, off));
    mx = fmaxf(mx, __shfl_xor(mx, off));
  }
}

__device__ inline float block_sum256(float v, float* sred){
  int t = threadIdx.x;
  #pragma unroll
  for (int off = 32; off > 0; off >>= 1) v += __shfl_xor(v, off);
  if ((t & 63) == 0) sred[t >> 6] = v;
  __syncthreads();
  float tot = sred[0] + sred[1] + sred[2] + sred[3];
  __syncthreads();
  return tot;
}

// ---------- K1: fused GEMM + max/argmax over Nb ----------
// one block per r = a*NS+s (1024 blocks). Computes dots of 100 vis rows x 192 word cols,
// reduces max/argmax over the 100, applies word mask, writes D_sim / D_ind(as float).
__global__ __launch_bounds__(256) void k_gemm_max(
    const float* __restrict__ vis, const float* __restrict__ word,
    const int* __restrict__ elen, float* __restrict__ dind, float* __restrict__ dsim)
{
  __shared__ float As[NB * 33];   // 100 x 32, pitch 33
  __shared__ float Bs[NC * 33];   // 192 x 32, pitch 33
  const int r  = blockIdx.x;
  const int t  = threadIdx.x;
  const int tc = t & 15;          // col group 0..15 -> c = jc*16+tc
  const int tb = t >> 4;          // row group 0..15 -> b = tb*7+j

  float acc[7][12];
  #pragma unroll
  for (int j = 0; j < 7; ++j)
    #pragma unroll
    for (int jc = 0; jc < 12; ++jc) acc[j][jc] = 0.f;

  const float* abase = vis + (size_t)r * NB * DD;

  for (int k0 = 0; k0 < DD; k0 += 32){
    for (int i = t; i < NB * 8; i += 256){
      int b = i >> 3, q = i & 7;
      const float4 v = *(const float4*)(abase + (size_t)b * DD + k0 + q * 4);
      float* d = &As[b * 33 + q * 4];
      d[0] = v.x; d[1] = v.y; d[2] = v.z; d[3] = v.w;
    }
    for (int i = t; i < NC * 8; i += 256){
      int c = i >> 3, q = i & 7;
      const float4 v = *(const float4*)(word + (size_t)c * DD + k0 + q * 4);
      float* d = &Bs[c * 33 + q * 4];
      d[0] = v.x; d[1] = v.y; d[2] = v.z; d[3] = v.w;
    }
    __syncthreads();
    #pragma unroll 4
    for (int kk = 0; kk < 32; ++kk){
      float breg[12], areg[7];
      #pragma unroll
      for (int jc = 0; jc < 12; ++jc) breg[jc] = Bs[(jc * 16 + tc) * 33 + kk];
      #pragma unroll
      for (int j = 0; j < 7; ++j){
        int b = tb * 7 + j; b = (b < NB) ? b : (NB - 1);
        areg[j] = As[b * 33 + kk];
      }
      #pragma unroll
      for (int j = 0; j < 7; ++j)
        #pragma unroll
        for (int jc = 0; jc < 12; ++jc)
          acc[j][jc] = fmaf(areg[j], breg[jc], acc[j][jc]);
    }
    __syncthreads();
  }

  // ---- max/argmax over b ----
  float* redv = As;   // 192*16 = 3072 floats, fits in As (3300)
  float* redi = Bs;
  #pragma unroll
  for (int jc = 0; jc < 12; ++jc){
    int c = jc * 16 + tc;
    float best = -3.4e38f; int bi = 0;
    #pragma unroll
    for (int j = 0; j < 7; ++j){
      int b = tb * 7 + j;
      if (b < NB){ float v = acc[j][jc]; if (v > best){ best = v; bi = b; } }
    }
    redv[c * 16 + tb] = best;
    redi[c * 16 + tb] = (float)bi;
  }
  __syncthreads();
  if (t < NC){
    int c = t;
    float best = -3.4e38f; int bi = 0;
    #pragma unroll
    for (int g = 0; g < 16; ++g){          // ascending tb == ascending b -> first-index tie-break
      float v = redv[c * 16 + g];
      if (v > best){ best = v; bi = (int)redi[c * 16 + g]; }
    }
    int aw = c / NE, e = c - aw * NE;
    if (e >= elen[aw]){ best = 0.f; bi = 0; }   // masked column: S_=0 everywhere -> max 0, argmax 0
    dsim[r * NC + c] = best;
    dind[r * NC + c] = (float)bi;
  }
}

// ---------- K2: IoU ----------
__global__ __launch_bounds__(256) void k_iou(
    const float* __restrict__ boxes, const float* __restrict__ det, float* __restrict__ out)
{
  int idx = blockIdx.x * 256 + threadIdx.x;
  const int total = NA * NS * NB * ML;
  if (idx >= total) return;
  int m = idx % ML; int t2 = idx / ML; int b = t2 % NB; int t3 = t2 / NB; // t3 = a*NS+s
  const float4 A = *(const float4*)(boxes + (size_t)(t3 * NB + b) * 4);
  int a = t3 / NS;
  const float4 B = *(const float4*)(det + (size_t)(a * ML + m) * 4);
  float iw = fminf(A.z, B.z) - fmaxf(A.x, B.x);
  float ih = fminf(A.w, B.w) - fmaxf(A.y, B.y);
  bool pos = (iw > 0.f) && (ih > 0.f);
  float inter = pos ? iw * ih : 0.f;
  float a1 = (A.z - A.x) * (A.w - A.y);
  float a2 = (B.z - B.x) * (B.w - B.y);
  float den = a1 + a2 - inter;
  out[idx] = pos ? inter / (den > 0.f ? den : 1.f) : 0.f;
}

// ---------- K3a: column-normalize D_sim over s, fold into Sf ----------
// grid (NA, NA), block 64 (one wave, thread = s)
__global__ void k_sf(const float* __restrict__ dsim, const int* __restrict__ elen,
                     float* __restrict__ sf)
{
  int a = blockIdx.x, aw = blockIdx.y, s = threadIdx.x;
  float accv = 0.f;
  for (int e = 0; e < NE; ++e){
    int c = aw * NE + e;
    float v = dsim[(a * NS + s) * NC + c];
    float mn, mx; wave_minmax64(v, mn, mx);
    accv += v * (v - mn) / (mx - mn + EPSF);
  }
  float dv = fmaxf((float)elen[aw], 1.f);
  sf[(a * NS + s) * NA + aw] = accv / dv;
}

// ---------- K3b: normalize diagonal sim scores; init accumulators ----------
// grid (NA, NE), block 64
__global__ void k_simnorm(const float* __restrict__ dsim, float* __restrict__ simn,
                          float* __restrict__ accums)
{
  int a = blockIdx.x, e = blockIdx.y, s = threadIdx.x;
  if (a == 0 && e == 0 && s == 0){ accums[0] = 0.f; accums[1] = 0.f; }
  float v = dsim[(a * NS + s) * NC + (a * NE + e)];
  float mn, mx; wave_minmax64(v, mn, mx);
  simn[(a * NS + s) * NE + e] = (v - mn) / (mx - mn + EPSF);
}

// ---------- K4: vis_loss via ||sum w||^2 identity (no 64x64 gram) ----------
// grid (NA, NE), block 256. gram.sum per (a,e) = 4032 - ||W||^2 + sum_s ||w_s||^2
__global__ __launch_bounds__(256) void k_gram(
    const float* __restrict__ vis, const float* __restrict__ dind,
    const float* __restrict__ simn, const int* __restrict__ elen,
    float* __restrict__ accums)
{
  int a = blockIdx.x, e = blockIdx.y;
  if (e >= elen[a]) return;               // masked (a,e): contributes 0 to sum and count
  __shared__ float sred[4];
  int t = threadIdx.x;
  float W0 = 0.f, W1 = 0.f, nw2 = 0.f;
  for (int s = 0; s < NS; ++s){
    float sn = simn[(a * NS + s) * NE + e];
    int mi = (int)dind[(a * NS + s) * NC + (a * NE + e)];
    const float* row = vis + (size_t)((a * NS + s) * NB + mi) * DD;
    float x0 = row[t], x1 = row[t + 256];
    float ss = block_sum256(x0 * x0 + x1 * x1, sred);
    float inv = sn / (sqrtf(ss) + EPSF);
    W0 = fmaf(x0, inv, W0);
    W1 = fmaf(x1, inv, W1);
    if (t == 0){
      float d = sqrtf(ss) + EPSF;
      nw2 += sn * sn * ss / (d * d);
    }
  }
  float w2 = block_sum256(W0 * W0 + W1 * W1, sred);
  if (t == 0){
    float part = (float)(NS * (NS - 1)) - w2 + nw2;
    atomicAdd(&accums[0], part);
    atomicAdd(&accums[1], (float)(NS * (NS - 1)));
  }
}

// ---------- K5: Sf margin terms + final loss ----------
__global__ __launch_bounds__(256) void k_final(
    const float* __restrict__ sf, const float* __restrict__ accums, float* __restrict__ out)
{
  __shared__ float sred[4];
  int t = threadIdx.x;
  float sum = 0.f;
  for (int i = t; i < NA * NS * NA; i += 256){
    int b = i & (NA - 1);
    int s = (i >> 4) & (NS - 1);
    int a = i >> 10;
    float v  = sf[i];                          // Sf[a,s,b]
    float d1 = sf[(b * NS + s) * NA + b];      // Sf_diag[b,s]
    float d2 = sf[(a * NS + s) * NA + a];      // Sf_diag[a,s]
    sum += fmaxf(v - d1 + DELTA_F, 0.f) + fmaxf(v - d2 + DELTA_F, 0.f);
  }
  float tot = block_sum256(sum, sred);
  if (t == 0){
    float frame = tot / (float)(NA * NA * NS);
    float cnt = accums[1];
    float vis_loss = accums[0] / fmaxf(cnt, 1.f);
    out[0] = (frame + vis_loss) * 10.f;
  }
}

// ---------- launch ----------
extern "C" void kernel_launch(void* const* d_in, const int* in_sizes, int n_in,
                              void* d_out, int out_size, void* d_ws, size_t ws_size,
                              hipStream_t stream)
{
  const float* vis   = (const float*)d_in[0];
  const float* word  = (const float*)d_in[1];
  const float* boxes = (const float*)d_in[2];
  const float* det   = (const float*)d_in[3];
  const int*   elen  = (const int*)d_in[4];

  float* out   = (float*)d_out;
  float* dind  = out;                       // 196608 (indices as float)
  float* dsim  = out + NR * NC;             // 196608
  float* mloss = out + 2 * NR * NC;         // 1
  float* dtin  = mloss + 1;                 // 2,048,000

  float* ws     = (float*)d_ws;
  float* sf     = ws;                       // 16*64*16 = 16384
  float* simn   = ws + NA * NS * NA;        // 16*64*12 = 12288
  float* accums = simn + NA * NS * NE;      // 2 floats

  k_gemm_max<<<NR, 256, 0, stream>>>(vis, word, elen, dind, dsim);
  k_iou<<<(NA * NS * NB * ML + 255) / 256, 256, 0, stream>>>(boxes, det, dtin);
  k_sf<<<dim3(NA, NA), 64, 0, stream>>>(dsim, elen, sf);
  k_simnorm<<<dim3(NA, NE), 64, 0, stream>>>(dsim, simn, accums);
  k_gram<<<dim3(NA, NE), 256, 0, stream>>>(vis, dind, simn, elen, accums);
  k_final<<<1, 256, 0, stream>>>(sf, accums, mloss);
}